// Round 6
// baseline (276.625 us; speedup 1.0000x reference)
//
#include <hip/hip_runtime.h>

#define OUT_W 1024
#define OUT_H 1024

typedef float f32x4 __attribute__((ext_vector_type(4)));

// ---------------------------------------------------------------------------
// Pass 1: zero the whole output in the rocclr-fill shape (grid-stride, few
// long-lived waves, each streaming many independent dwordx4 stores). The
// harness's own fillBufferAligned sustains 6.6 TB/s in exactly this shape.
// ---------------------------------------------------------------------------
__global__ __launch_bounds__(256)
void zero_kernel(f32x4* __restrict__ out, int n4)
{
    const int nthreads = gridDim.x * blockDim.x;
    const f32x4 z = {0.0f, 0.0f, 0.0f, 0.0f};
    int i = blockIdx.x * blockDim.x + threadIdx.x;
#pragma unroll 8
    for (; i < n4; i += nthreads)
        out[i] = z;
}

// ---------------------------------------------------------------------------
// Pass 2: sparse splat. One wave (64 lanes) per box; writes ONLY the Gaussian
// span of each row (span <= 197 since wh < 200), ~28 MiB total instead of
// 256 MiB. ul/br/x/y are integer-valued floats (|v| < 2^24) so (int) trunc
// is exact and the [lo,hi) loop reproduces the reference mask exactly.
// ---------------------------------------------------------------------------
__global__ __launch_bounds__(256)
void splat_kernel(const float* __restrict__ center,
                  const float* __restrict__ wh,
                  float* __restrict__ out_x,
                  float* __restrict__ out_y,
                  int bn_total)
{
    const int lane = threadIdx.x & 63;
    const int bn   = blockIdx.x * 4 + (threadIdx.x >> 6);
    if (bn >= bn_total) return;

    const float2 c = reinterpret_cast<const float2*>(center)[bn];
    const float2 w = reinterpret_cast<const float2*>(wh)[bn];
    const float cx = c.x, cy = c.y, Wb = w.x, Hb = w.y;

    // ks = floor(W/2)*2 - 1 ; r = floor((ks-1)/2) ; sigma = floor(r/3)
    const float ksw = floorf(Wb * 0.5f) * 2.0f - 1.0f;
    const float rw  = floorf((ksw - 1.0f) * 0.5f);
    const float sw  = floorf(rw / 3.0f);
    const float ksh = floorf(Hb * 0.5f) * 2.0f - 1.0f;
    const float rh  = floorf((ksh - 1.0f) * 0.5f);
    const float sh  = floorf(rh / 3.0f);

    const bool zero_box = ((cx + cy) + (Wb + Hb)) == 0.0f;

    // SCALE = 1.0 ; trunc toward zero (astype(int32))
    const float x = truncf(cx);
    const float y = truncf(cy);

    const float ul0 = x - rw;
    const float ul1 = y - rh;
    const float br0 = x + rw + 1.0f;
    const float br1 = y + rh + 1.0f;

    const bool in_ul = (ul0 >= 0.0f) && (ul0 <= (float)OUT_W) &&
                       (ul1 >= 0.0f) && (ul1 <= (float)OUT_H);
    const bool in_br = (br0 >= 0.0f) && (br0 <= (float)OUT_W) &&
                       (br1 >= 0.0f) && (br1 <= (float)OUT_H);
    const bool active = (!zero_box) && (sw != 0.0f) && (sh != 0.0f) && (in_ul || in_br);
    if (!active) return;   // wave-uniform: zeros already written by pass 1

    const float iw = -1.0f / (2.0f * sw * sw);
    const float ih = -1.0f / (2.0f * sh * sh);

    // x-row span
    {
        float* row = out_x + (size_t)bn * OUT_W;
        const int lo = max(0, (int)ul0);
        const int hi = min(OUT_W, (int)br0);
        for (int p = lo + lane; p < hi; p += 64) {
            const float d = (float)p - x;
            row[p] = __expf(d * d * iw);
        }
    }
    // y-row span
    {
        float* row = out_y + (size_t)bn * OUT_H;
        const int lo = max(0, (int)ul1);
        const int hi = min(OUT_H, (int)br1);
        for (int p = lo + lane; p < hi; p += 64) {
            const float d = (float)p - y;
            row[p] = __expf(d * d * ih);
        }
    }
}

extern "C" void kernel_launch(void* const* d_in, const int* in_sizes, int n_in,
                              void* d_out, int out_size, void* d_ws, size_t ws_size,
                              hipStream_t stream) {
    const float* center = (const float*)d_in[0];  // [B,N,2]
    const float* wh     = (const float*)d_in[1];  // [B,N,2]
    float* out = (float*)d_out;                   // vector_x ++ vector_y, fp32

    const int BN = in_sizes[0] / 2;               // B*N = 32768
    float* out_x = out;
    float* out_y = out + (size_t)BN * OUT_W;

    // Pass 1: zero 2*BN*1024 floats = out_size elements
    const int n4 = out_size / 4;
    zero_kernel<<<dim3(2048), dim3(256), 0, stream>>>((f32x4*)out, n4);

    // Pass 2: sparse Gaussian splat, 4 boxes per 256-thread block (1 wave/box)
    const int grid = (BN + 3) / 4;
    splat_kernel<<<dim3(grid), dim3(256), 0, stream>>>(center, wh, out_x, out_y, BN);
}